// Round 9
// baseline (483.191 us; speedup 1.0000x reference)
//
#include <hip/hip_runtime.h>
#include <hip/hip_bf16.h>
#include <stdint.h>

// ConvIntrinsic: fused  out[k,o,t] = relu( Σ_f sw[t,f]·ms[k,f]
//                + Σ_{x,y,f} W3[o,t,x,y,f]·interp0[k,x,y,f] + bias[t] )
// => GEMM (K=100000 × 1312) @ (1312 × 768), o=8 column duplicates o=0.
//
// R8: EA-byte reduction on the gather path. R1/R2/R3/R7 all track EA bytes
// at ~2.7-3.0 TB/s => EA-bound, and ~700 MB of FETCH is random ms-gather
// L2 misses (ms = 12.8 MB fp32 vs 4 MiB/XCD L2; each vertex row = 2 lines).
// Fix: prep_ms converts ms -> bf16 table msb (6.4 MB in d_ws): one vertex
// row = 32 bf16 = 64 B = ONE line (halves gather line traffic, doubles
// L2-resident fraction). A-build: 4 thr/row x 8 bf16 cols, short8 gathers,
// fp32 interp after bf16 unpack (center chunk is exact pass-through).
// Skeleton (geometry/pipeline/barrier/epilogue) is R7-verbatim.

typedef __attribute__((ext_vector_type(8))) short short8;
typedef __attribute__((ext_vector_type(4))) float floatx4;
typedef __attribute__((ext_vector_type(2))) float fx2;

#define KPTS 100000
#define OUT_STRIDE 864   // 9*96
#define BM 64
#define THREADS 512
#define BP_SHORTS 1007616   // 41*48*64*8 (Bp element count; byte off 2015232, 16B-aligned)

// Workgroup barrier without vmcnt drain (R7 form).
#define BARRIER() do {                              \
    __builtin_amdgcn_sched_barrier(0);              \
    asm volatile("s_waitcnt lgkmcnt(0)");           \
    __builtin_amdgcn_s_barrier();                   \
  } while (0)

__device__ __forceinline__ short f2bf(float x) {
  union { float f; uint32_t u; } c; c.f = x;
  uint32_t u = c.u;
  u += 0x7FFFu + ((u >> 16) & 1u);   // round-to-nearest-even
  return (short)(u >> 16);
}
__device__ __forceinline__ float bf2f(short s) {
  union { uint32_t u; float f; } c;
  c.u = ((uint32_t)(uint16_t)s) << 16;
  return c.f;
}

// ---------------- prep: ms -> bf16 table --------------------------------
__global__ void prep_ms(const float* __restrict__ ms, short* __restrict__ msb) {
  const int i = (blockIdx.x * 256 + threadIdx.x) * 8;
  if (i < KPTS * 32) {
    floatx4 a = *(const floatx4*)(ms + i);
    floatx4 b = *(const floatx4*)(ms + i + 4);
    short8 s;
#pragma unroll
    for (int j = 0; j < 4; ++j) { s[j] = f2bf(a[j]); s[4 + j] = f2bf(b[j]); }
    *reinterpret_cast<short8*>(msb + i) = s;
  }
}

// ---------------- prep: pack B in MFMA fragment layout --------------------
// Bp[ch][ntile][lane][j] = B[c = ch*32 + (lane>>4)*8 + j][n = ntile*16 + (lane&15)]
__global__ void prep_B(const float* __restrict__ kern,
                       const float* __restrict__ tw,
                       const float* __restrict__ sw,
                       short* __restrict__ Bp) {
  const int ntile = blockIdx.x;   // 0..47
  const int ch    = blockIdx.y;   // 0..40
  const int lane  = threadIdx.x;  // 0..63
  const int n = ntile * 16 + (lane & 15);
  const int o = n / 96;
  const int t = n - o * 96;
  const int fb = (lane >> 4) * 8;

  short8 v;
  if (ch < 40) {
    float kcol[40];
#pragma unroll
    for (int ra = 0; ra < 40; ++ra) kcol[ra] = kern[ra * 40 + ch];
#pragma unroll
    for (int j = 0; j < 8; ++j) {
      const int f = fb + j;
      float acc = 0.f;
      for (int r = 0; r < 5; ++r) {
#pragma unroll
        for (int a = 0; a < 8; ++a) {
          acc += kcol[r * 8 + a] * tw[((t * 5 + r) * 8 + ((a + o) & 7)) * 32 + f];
        }
      }
      v[j] = f2bf(acc);
    }
  } else {
#pragma unroll
    for (int j = 0; j < 8; ++j) v[j] = f2bf(sw[t * 32 + fb + j]);
  }
  *reinterpret_cast<short8*>(Bp + ((size_t)(ch * 48 + ntile) * 64 + lane) * 8) = v;
}

// ---------------- main fused GEMM ----------------------------------------
__global__ __launch_bounds__(THREADS, 1) void conv_main(
    const short* __restrict__ msb,
    const float* __restrict__ bary,
    const float* __restrict__ bias,
    const short* __restrict__ Bp,
    float* __restrict__ out) {
  __shared__ short Atile[2][BM][40];   // 32 used cols + 8 pad shorts

  const int kbase = blockIdx.x * BM;
  const int tid = threadIdx.x;
  const int lane = tid & 63;
  const int wn = tid >> 6;             // 0..7  (wave n-group: cols wn*96)
  const int l15 = lane & 15;
  const int kh = lane >> 4;            // 0..3

  // A-build role: 4 threads per row, 8 bf16 f-columns each; 256 builders.
  const bool builder = tid < 256;
  const int arow = tid >> 2;           // 0..63 for builders
  const int af0 = (tid & 3) * 8;       // 0,8,16,24
  const int krow = kbase + (arow & 63);
  const bool rowok = builder && (krow < KPTS);
  const float* __restrict__ brow = bary + (size_t)(rowok ? krow : 0) * 240;
  const short* __restrict__ mrowb = msb + (size_t)(rowok ? krow : 0) * 32 + af0;

  // bary register sets (chunk parity): loaded 1 iter before use
  fx2 bE0, bE1, bE2, bO0, bO1, bO2;
  // gather register sets (chunk parity): issued 1 full iter before commit
  short8 eG0, eG1, eG2, oG0, oG1, oG2;
  float eW0, eW1, eW2, oW0, oW1, oW2;

  auto ldbary = [&](int c, fx2& p0, fx2& p1, fx2& p2) {
    if (rowok) {
      const fx2* bp = (const fx2*)(brow + c * 6);
      p0 = __builtin_nontemporal_load(bp);
      p1 = __builtin_nontemporal_load(bp + 1);
      p2 = __builtin_nontemporal_load(bp + 2);
    } else {
      p0 = (fx2)0.f; p1 = (fx2)0.f; p2 = (fx2)0.f;
    }
  };
  auto issueG = [&](int c, const fx2& p0, const fx2& p1, const fx2& p2,
                    short8& A, short8& B, short8& C,
                    float& W0, float& W1, float& W2) {
    if (c == 40) {   // center chunk: A[k][1280+f] = ms[k][f] (exact pass-through)
      A = *(const short8*)(mrowb);
      B = A; C = A;
      W0 = rowok ? 1.f : 0.f; W1 = 0.f; W2 = 0.f;
    } else {
      A = *(const short8*)(msb + ((size_t)(int)p0.x) * 32 + af0);
      B = *(const short8*)(msb + ((size_t)(int)p1.x) * 32 + af0);
      C = *(const short8*)(msb + ((size_t)(int)p2.x) * 32 + af0);
      W0 = p0.y; W1 = p1.y; W2 = p2.y;
    }
  };
  auto commitG = [&](const short8& A, const short8& B, const short8& C,
                     float W0, float W1, float W2, int buf) {
    short8 s;
#pragma unroll
    for (int j = 0; j < 8; ++j)
      s[j] = f2bf(W0 * bf2f(A[j]) + W1 * bf2f(B[j]) + W2 * bf2f(C[j]));
    *reinterpret_cast<short8*>(&Atile[buf][arow][af0]) = s;
  };

  short8 bfA[6], bfB[6];
  auto loadB = [&](int c, short8* dst) {
    const short* bp = Bp + ((size_t)(c * 48 + wn * 6) * 64 + lane) * 8;
#pragma unroll
    for (int j = 0; j < 6; ++j)
      dst[j] = *reinterpret_cast<const short8*>(bp + (size_t)j * 512);
  };

  floatx4 acc[4][6];
#pragma unroll
  for (int mi = 0; mi < 4; ++mi)
#pragma unroll
    for (int nj = 0; nj < 6; ++nj) acc[mi][nj] = (floatx4)0.f;

  // ---- prologue ----
  if (builder) {
    fx2 t0, t1, t2;
    ldbary(0, t0, t1, t2);
    issueG(0, t0, t1, t2, eG0, eG1, eG2, eW0, eW1, eW2);
    ldbary(1, t0, t1, t2);
    issueG(1, t0, t1, t2, oG0, oG1, oG2, oW0, oW1, oW2);
    ldbary(2, bE0, bE1, bE2);                  // for issue(2) at iter 0
    commitG(eG0, eG1, eG2, eW0, eW1, eW2, 0);  // chunk 0 -> Atile[0]
  }
  loadB(0, bfA);
  BARRIER();

  // iter ch: issue(ch+2) with bary set (ch&1); ldbary(ch+3) -> other set;
  // MFMA chunk ch from Atile[ch&1] with B-set BF; loadB(ch+1) -> NBF;
  // commit(ch+1) -> Atile[(ch&1)^1]; barrier (global loads stay in flight).
#define ITER(ch, UB0, UB1, UB2, FB0, FB1, FB2,                                  \
             FG0, FG1, FG2, FW0, FW1, FW2,                                      \
             CG0, CG1, CG2, CW0, CW1, CW2, CUR, BF, NBF)                        \
  {                                                                             \
    if (builder) {                                                              \
      if ((ch) + 2 <= 40)                                                       \
        issueG((ch) + 2, UB0, UB1, UB2, FG0, FG1, FG2, FW0, FW1, FW2);          \
      if ((ch) + 3 <= 39) ldbary((ch) + 3, FB0, FB1, FB2);                      \
    }                                                                           \
    short8 af[4];                                                               \
    _Pragma("unroll")                                                           \
    for (int mi = 0; mi < 4; ++mi)                                              \
      af[mi] = *reinterpret_cast<const short8*>(&Atile[CUR][mi * 16 + l15][kh * 8]); \
    if ((ch) + 1 <= 40) loadB((ch) + 1, NBF);                                   \
    _Pragma("unroll")                                                           \
    for (int nj = 0; nj < 6; ++nj)                                              \
      _Pragma("unroll")                                                         \
      for (int mi = 0; mi < 4; ++mi)                                            \
        acc[mi][nj] = __builtin_amdgcn_mfma_f32_16x16x32_bf16(af[mi], BF[nj],   \
                                                              acc[mi][nj], 0, 0, 0); \
    if (builder && (ch) + 1 <= 40)                                              \
      commitG(CG0, CG1, CG2, CW0, CW1, CW2, (CUR) ^ 1);                         \
    BARRIER();                                                                  \
  }

  for (int ch = 0; ch < 40; ch += 2) {
    // even iter: use bE, fill bO; fill E gathers, commit O gathers; Atile[0]; B=bfA
    ITER(ch,     bE0, bE1, bE2, bO0, bO1, bO2,
         eG0, eG1, eG2, eW0, eW1, eW2,
         oG0, oG1, oG2, oW0, oW1, oW2, 0, bfA, bfB)
    // odd iter: use bO, fill bE; fill O gathers, commit E gathers; Atile[1]; B=bfB
    ITER(ch + 1, bO0, bO1, bO2, bE0, bE1, bE2,
         oG0, oG1, oG2, oW0, oW1, oW2,
         eG0, eG1, eG2, eW0, eW1, eW2, 1, bfB, bfA)
  }
  ITER(40, bE0, bE1, bE2, bO0, bO1, bO2,
       eG0, eG1, eG2, eW0, eW1, eW2,
       oG0, oG1, oG2, oW0, oW1, oW2, 0, bfA, bfB)
#undef ITER

  // epilogue: bias + relu; out[k,o,t] = out[k*864 + n]; o=8 duplicates o=0
#pragma unroll
  for (int mi = 0; mi < 4; ++mi) {
    const int rb = kbase + mi * 16 + kh * 4;
#pragma unroll
    for (int nj = 0; nj < 6; ++nj) {
      const int n = wn * 96 + nj * 16 + l15;
      const float bsv = bias[nj * 16 + l15];
      const bool dup = (wn == 0);
#pragma unroll
      for (int i = 0; i < 4; ++i) {
        const int r = rb + i;
        if (r < KPTS) {
          float vv = fmaxf(acc[mi][nj][i] + bsv, 0.f);
          out[(size_t)r * OUT_STRIDE + n] = vv;
          if (dup) out[(size_t)r * OUT_STRIDE + 768 + n] = vv;
        }
      }
    }
  }
}

extern "C" void kernel_launch(void* const* d_in, const int* in_sizes, int n_in,
                              void* d_out, int out_size, void* d_ws, size_t ws_size,
                              hipStream_t stream) {
  const float* ms   = (const float*)d_in[0];  // (K,32)
  const float* bary = (const float*)d_in[1];  // (K,5,8,3,2)
  const float* kern = (const float*)d_in[2];  // (5,8,5,8)
  const float* tw   = (const float*)d_in[3];  // (96,5,8,32)
  const float* sw   = (const float*)d_in[4];  // (96,1,32)
  const float* bias = (const float*)d_in[5];  // (96,)
  float* out = (float*)d_out;
  short* Bp  = (short*)d_ws;                  // 2.02 MB
  short* msb = (short*)d_ws + BP_SHORTS;      // bf16 ms table, 6.4 MB

  hipLaunchKernelGGL(prep_B, dim3(48, 41), dim3(64), 0, stream, kern, tw, sw, Bp);
  hipLaunchKernelGGL(prep_ms, dim3((KPTS * 32 / 8 + 255) / 256), dim3(256), 0, stream,
                     ms, msb);
  hipLaunchKernelGGL(conv_main, dim3(1563), dim3(THREADS), 0, stream,
                     msb, bary, bias, Bp, out);
}